// Round 15
// baseline (30752.383 us; speedup 1.0000x reference)
//
#include <hip/hip_runtime.h>
#include <math.h>

typedef unsigned int u32;

#define T_    600
#define FIN_  120

// ---- ws byte offsets ----
#define OFF_BAR      0ull          // 2048 B: arrive[256]; enc flags 257..264; dec flags 272..275
#define OFF_HENC     2048ull       // [2 parity][2 dir][512][32]
#define OFF_CENC     264192ull     // (unused)
#define OFF_HD       395264ull     // [2 parity][32][512]
#define OFF_CD       526336ull     // [32][512]
#define STATE_BYTES  591872ull     // memset-0 region
#define OFF_LAST     591872ull     // [32][512]
#define OFF_Q        657408ull     // [32][512]
#define OFF_CTX      722944ull     // [32][1024]
#define OFF_SCORES   854016ull     // [32][600]
#define OFF_STATS    930816ull     // (legacy, unused)
#define OFF_AUDIOT   931840ull     // [600][120][32]
#define OFF_ENC2     10147840ull   // [32][1024][600]; decoder reuses: ctx_ch[32][8][1024], Mch, Sch
#define OFF_KEYT     88791040ull   // key_bt [32][600][512]
#define OFF_VAL      128112640ull  // val [32][600][1024]

__device__ __forceinline__ float sigf(float x) { return 1.0f / (1.0f + expf(-x)); }
__device__ __forceinline__ u32 umin4(u32 a, u32 b, u32 c, u32 d) {
  u32 x = a < b ? a : b; u32 y = c < d ? c : d; return x < y ? x : y;
}
// L3-coherent scalar access — bypasses non-coherent L2.
__device__ __forceinline__ void st_sys(float* p, float v) {
  __hip_atomic_store(p, v, __ATOMIC_RELAXED, __HIP_MEMORY_SCOPE_AGENT);
}
__device__ __forceinline__ float ld_sys(const float* p) {
  return __hip_atomic_load(p, __ATOMIC_RELAXED, __HIP_MEMORY_SCOPE_AGENT);
}
#define VM_FENCE() asm volatile("s_waitcnt vmcnt(0)" ::: "memory")
#define C_FENCE()  asm volatile("" ::: "memory")

// unified h+x LDS address: k in [0,632), b in [0,8). 2-float pad per 32-k chunk.
__device__ __forceinline__ int haddr(int k, int b) { return k * 8 + (k >> 5) * 2 + b; }

// ---------------- prep ----------------
__global__ __launch_bounds__(256) void k_prep_audio(const float* __restrict__ audio,
                                                    float* __restrict__ audio_T) {
  int idx = blockIdx.x * 256 + threadIdx.x;
  if (idx >= T_ * FIN_ * 32) return;
  int b = idx & 31;
  int r = idx >> 5;
  int f = r % FIN_;
  int t = r / FIN_;
  audio_T[idx] = audio[(size_t)b * (T_ * FIN_) + t * FIN_ + f];
}

__global__ __launch_bounds__(256) void k_init_last(const float* __restrict__ E,
                                                   float* __restrict__ last) {
  int idx = blockIdx.x * 256 + threadIdx.x;
  if (idx < 32 * 512) last[idx] = E[idx & 511];
}

// ---------------- persistent encoder: 8 groups (dir x bquad) x 32 blocks x 512 thr ----------------
// thread = (j_lo 16) x (kc 16) x (b_lo 2); 4 gates x 4 batches per thread; weight redundancy 2x.
struct EncP {
  const float* audio_T;
  const float* Wih_f; const float* Whh_f; const float* b_f;
  const float* Wih_b; const float* Whh_b; const float* b_b;
  float* h_enc; float* enc2;
  u32* bar;
};

__global__ __launch_bounds__(512) void k_encoder(EncP P) {
  __shared__ float hl[5096];          // unified h(512k)+x(120k) staged, k-major, chunk-padded
  __shared__ float hsave[4096];       // [128 r][32 slot] enc2 write-combine
  const int tid = threadIdx.x, bid = blockIdx.x;
  const int grp = bid >> 5;           // 0..7 = dir*4 + bquad
  const int dir = grp >> 2, bquad = grp & 3;
  const int jblk = bid & 31;
  const int j_lo = tid >> 5;          // 0..15
  const int kc   = (tid >> 1) & 15;   // 0..15
  const int b_lo = tid & 1;           // 0..1 -> batches b_lo*4 .. +4
  const int j = jblk * 16 + j_lo;
  const float* Wih  = dir ? P.Wih_b : P.Wih_f;
  const float* Whh  = dir ? P.Whh_b : P.Whh_f;
  const float* bias = dir ? P.b_b   : P.b_f;
  u32* arrive = P.bar + grp * 32;
  u32* flag   = P.bar + 257 + grp;

  const float* WA0 = Whh + (size_t)(j       ) * 512 + kc * 32;
  const float* WA1 = Whh + (size_t)(512  + j) * 512 + kc * 32;
  const float* WA2 = Whh + (size_t)(1024 + j) * 512 + kc * 32;
  const float* WA3 = Whh + (size_t)(1536 + j) * 512 + kc * 32;
  const float* IA0 = Wih + (size_t)(j       ) * 120 + kc * 8;
  const float* IA1 = Wih + (size_t)(512  + j) * 120 + kc * 8;
  const float* IA2 = Wih + (size_t)(1024 + j) * 120 + kc * 8;
  const float* IA3 = Wih + (size_t)(1536 + j) * 120 + kc * 8;
  const float bia0 = bias[j], bia1 = bias[512 + j], bia2 = bias[1024 + j], bia3 = bias[1536 + j];

  float c0 = 0.f, c1 = 0.f, c2 = 0.f, c3 = 0.f;   // cell states (kc==0 lanes)

  for (int s = 0; s < 600; s++) {
    const int t = dir ? (599 - s) : s;
    const int p = s & 1;
    // ---- stage h (k<512, ld_sys) + audio (k>=512, plain) : prefetch then write ----
    {
      const float* hsrc = P.h_enc + (size_t)(p * 2 + dir) * 16384 + bquad * 8;
      const float* xg = P.audio_T + (size_t)t * 3840 + bquad * 8;
      float v[10];
      #pragma unroll
      for (int u = 0; u < 10; u++) {
        int idx = u * 512 + tid;
        int k = idx >> 3, b = idx & 7;
        if (idx < 5056)
          v[u] = (k < 512) ? ld_sys(hsrc + k * 32 + b) : xg[(k - 512) * 32 + b];
      }
      #pragma unroll
      for (int u = 0; u < 10; u++) {
        int idx = u * 512 + tid;
        int k = idx >> 3, b = idx & 7;
        if (idx < 5056) hl[haddr(k, b)] = v[u];
      }
    }
    __syncthreads();

    // acc[gate][batch]
    float a00=0.f,a01=0.f,a02=0.f,a03=0.f;
    float a10=0.f,a11=0.f,a12=0.f,a13=0.f;
    float a20=0.f,a21=0.f,a22=0.f,a23=0.f;
    float a30=0.f,a31=0.f,a32=0.f,a33=0.f;
    const int boff = b_lo * 4;
    // Whh chunk: 32 k
    {
      const int k0 = kc * 32;
      #pragma unroll
      for (int m = 0; m < 32; m += 4) {
        float4 w0 = *(const float4*)(WA0 + m);
        float4 w1 = *(const float4*)(WA1 + m);
        float4 w2 = *(const float4*)(WA2 + m);
        float4 w3 = *(const float4*)(WA3 + m);
        const int base = (k0 + m) * 8 + kc * 2 + boff;
        #pragma unroll
        for (int d = 0; d < 4; d++) {
          float x0 = hl[base + d * 8 + 0];
          float x1 = hl[base + d * 8 + 1];
          float x2 = hl[base + d * 8 + 2];
          float x3 = hl[base + d * 8 + 3];
          float f0 = (d == 0) ? w0.x : (d == 1) ? w0.y : (d == 2) ? w0.z : w0.w;
          float f1 = (d == 0) ? w1.x : (d == 1) ? w1.y : (d == 2) ? w1.z : w1.w;
          float f2 = (d == 0) ? w2.x : (d == 1) ? w2.y : (d == 2) ? w2.z : w2.w;
          float f3 = (d == 0) ? w3.x : (d == 1) ? w3.y : (d == 2) ? w3.z : w3.w;
          a00 += f0 * x0; a01 += f0 * x1; a02 += f0 * x2; a03 += f0 * x3;
          a10 += f1 * x0; a11 += f1 * x1; a12 += f1 * x2; a13 += f1 * x3;
          a20 += f2 * x0; a21 += f2 * x1; a22 += f2 * x2; a23 += f2 * x3;
          a30 += f3 * x0; a31 += f3 * x1; a32 += f3 * x2; a33 += f3 * x3;
        }
      }
    }
    // Wih chunk: 8 k (kc < 15)
    if (kc < 15) {
      #pragma unroll
      for (int m = 0; m < 8; m += 4) {
        float4 w0 = *(const float4*)(IA0 + m);
        float4 w1 = *(const float4*)(IA1 + m);
        float4 w2 = *(const float4*)(IA2 + m);
        float4 w3 = *(const float4*)(IA3 + m);
        const int k = 512 + kc * 8 + m;
        const int base = k * 8 + (k >> 5) * 2 + boff;
        #pragma unroll
        for (int d = 0; d < 4; d++) {
          float x0 = hl[base + d * 8 + 0];
          float x1 = hl[base + d * 8 + 1];
          float x2 = hl[base + d * 8 + 2];
          float x3 = hl[base + d * 8 + 3];
          float f0 = (d == 0) ? w0.x : (d == 1) ? w0.y : (d == 2) ? w0.z : w0.w;
          float f1 = (d == 0) ? w1.x : (d == 1) ? w1.y : (d == 2) ? w1.z : w1.w;
          float f2 = (d == 0) ? w2.x : (d == 1) ? w2.y : (d == 2) ? w2.z : w2.w;
          float f3 = (d == 0) ? w3.x : (d == 1) ? w3.y : (d == 2) ? w3.z : w3.w;
          a00 += f0 * x0; a01 += f0 * x1; a02 += f0 * x2; a03 += f0 * x3;
          a10 += f1 * x0; a11 += f1 * x1; a12 += f1 * x2; a13 += f1 * x3;
          a20 += f2 * x0; a21 += f2 * x1; a22 += f2 * x2; a23 += f2 * x3;
          a30 += f3 * x0; a31 += f3 * x1; a32 += f3 * x2; a33 += f3 * x3;
        }
      }
    }
    // reduce across kc (lane bits 1..4)
    #pragma unroll
    for (int msk = 2; msk <= 16; msk <<= 1) {
      a00 += __shfl_xor(a00, msk); a01 += __shfl_xor(a01, msk);
      a02 += __shfl_xor(a02, msk); a03 += __shfl_xor(a03, msk);
      a10 += __shfl_xor(a10, msk); a11 += __shfl_xor(a11, msk);
      a12 += __shfl_xor(a12, msk); a13 += __shfl_xor(a13, msk);
      a20 += __shfl_xor(a20, msk); a21 += __shfl_xor(a21, msk);
      a22 += __shfl_xor(a22, msk); a23 += __shfl_xor(a23, msk);
      a30 += __shfl_xor(a30, msk); a31 += __shfl_xor(a31, msk);
      a32 += __shfl_xor(a32, msk); a33 += __shfl_xor(a33, msk);
    }
    if (kc == 0) {
      float* hdst = P.h_enc + (size_t)((p ^ 1) * 2 + dir) * 16384 + j * 32 + bquad * 8 + boff;
      {
        float cn = sigf(a10 + bia1) * c0 + sigf(a00 + bia0) * tanhf(a20 + bia2);
        c0 = cn;
        float hn = sigf(a30 + bia3) * tanhf(cn);
        st_sys(hdst + 0, hn);
        int r = j_lo * 8 + boff + 0; hsave[r * 32 + ((t + r) & 31)] = hn;
      }
      {
        float cn = sigf(a11 + bia1) * c1 + sigf(a01 + bia0) * tanhf(a21 + bia2);
        c1 = cn;
        float hn = sigf(a31 + bia3) * tanhf(cn);
        st_sys(hdst + 1, hn);
        int r = j_lo * 8 + boff + 1; hsave[r * 32 + ((t + r) & 31)] = hn;
      }
      {
        float cn = sigf(a12 + bia1) * c2 + sigf(a02 + bia0) * tanhf(a22 + bia2);
        c2 = cn;
        float hn = sigf(a32 + bia3) * tanhf(cn);
        st_sys(hdst + 2, hn);
        int r = j_lo * 8 + boff + 2; hsave[r * 32 + ((t + r) & 31)] = hn;
      }
      {
        float cn = sigf(a13 + bia1) * c3 + sigf(a03 + bia0) * tanhf(a23 + bia2);
        c3 = cn;
        float hn = sigf(a33 + bia3) * tanhf(cn);
        st_sys(hdst + 3, hn);
        int r = j_lo * 8 + boff + 3; hsave[r * 32 + ((t + r) & 31)] = hn;
      }
    }
    // ---- barrier + deferred enc2 flush ----
    VM_FENCE();
    __syncthreads();
    const u32 target = (u32)(s + 1);
    if (tid == 0)
      __hip_atomic_store(&arrive[jblk], target, __ATOMIC_RELAXED, __HIP_MEMORY_SCOPE_AGENT);
    {
      bool doflush = dir ? ((t & 31) == 0) : (((t & 31) == 31) || (t == 599));
      int tbase = dir ? t : ((t == 599) ? 576 : (t - 31));
      if (doflush) {
        const int fmaxv = 599 - tbase;
        for (int idx = tid; idx < 4096; idx += 512) {
          int r = idx >> 5, f = idx & 31;
          if (f <= fmaxv) {
            float v = hsave[r * 32 + ((tbase + f + r) & 31)];
            int jl = r >> 3, bl = r & 7;
            P.enc2[(size_t)(bquad * 8 + bl) * 614400 +
                   (size_t)(dir * 512 + jblk * 16 + jl) * 600 + tbase + f] = v;
          }
        }
      }
    }
    if (jblk == (s & 31)) {
      if (tid < 8) {
        const int base = tid * 4;
        for (;;) {
          u32 a0_ = __hip_atomic_load(&arrive[base + 0], __ATOMIC_RELAXED, __HIP_MEMORY_SCOPE_AGENT);
          u32 a1_ = __hip_atomic_load(&arrive[base + 1], __ATOMIC_RELAXED, __HIP_MEMORY_SCOPE_AGENT);
          u32 a2_ = __hip_atomic_load(&arrive[base + 2], __ATOMIC_RELAXED, __HIP_MEMORY_SCOPE_AGENT);
          u32 a3_ = __hip_atomic_load(&arrive[base + 3], __ATOMIC_RELAXED, __HIP_MEMORY_SCOPE_AGENT);
          if (__all(umin4(a0_, a1_, a2_, a3_) >= target)) break;
          __builtin_amdgcn_s_sleep(1);
        }
        if (tid == 0)
          __hip_atomic_store(flag, target, __ATOMIC_RELAXED, __HIP_MEMORY_SCOPE_AGENT);
      }
    }
    if (tid == 0) {
      while (__hip_atomic_load(flag, __ATOMIC_RELAXED, __HIP_MEMORY_SCOPE_AGENT) < target)
        __builtin_amdgcn_s_sleep(2);
    }
    C_FENCE();
    __syncthreads();
  }
}

// ---------------- key/val GEMM: key -> [b][t][k], val -> [b][t][w] ----------------
struct KVP {
  const float* enc2; const float* Wk; const float* bk; const float* Wv; const float* bv;
  float* key_bt; float* val;
};

__global__ __launch_bounds__(256) void k_keyval(KVP P) {
  __shared__ float As[16 * 132];
  __shared__ float Bs[16 * 132];
  const int tid = threadIdx.x, bid = blockIdx.x;
  const int mt = bid % 150, nt = bid / 150;
  const int m0 = mt * 128, n0 = nt * 128;
  const int tx = tid & 15, ty = tid >> 4;
  const int mmS = tid & 127;
  const int gmS = m0 + mmS;
  const int bS = gmS / 600, tS = gmS % 600;
  const int kkS0 = tid >> 7;
  const int nnS0 = tid >> 4;
  const int kkSB = tid & 15;
  float acc[8][8];
  #pragma unroll
  for (int i = 0; i < 8; i++)
    #pragma unroll
    for (int jj = 0; jj < 8; jj++) acc[i][jj] = 0.f;
  for (int k0 = 0; k0 < 1024; k0 += 16) {
    #pragma unroll
    for (int r = 0; r < 8; r++) {
      int kk = kkS0 + 2 * r;
      As[kk * 132 + mmS] = P.enc2[(size_t)bS * 614400 + (size_t)(k0 + kk) * 600 + tS];
    }
    #pragma unroll
    for (int r = 0; r < 8; r++) {
      int nn = nnS0 + 16 * r;
      int n = n0 + nn;
      const float* src = (n < 512) ? (P.Wk + (size_t)n * 1024) : (P.Wv + (size_t)(n - 512) * 1024);
      Bs[kkSB * 132 + nn] = src[k0 + kkSB];
    }
    __syncthreads();
    #pragma unroll
    for (int kk = 0; kk < 16; kk++) {
      float4 A0 = *(const float4*)&As[kk * 132 + ty * 8];
      float4 A1 = *(const float4*)&As[kk * 132 + ty * 8 + 4];
      float4 B0 = *(const float4*)&Bs[kk * 132 + tx * 8];
      float4 B1 = *(const float4*)&Bs[kk * 132 + tx * 8 + 4];
      float av[8] = {A0.x, A0.y, A0.z, A0.w, A1.x, A1.y, A1.z, A1.w};
      float bw[8] = {B0.x, B0.y, B0.z, B0.w, B1.x, B1.y, B1.z, B1.w};
      #pragma unroll
      for (int i = 0; i < 8; i++)
        #pragma unroll
        for (int jj = 0; jj < 8; jj++) acc[i][jj] += av[i] * bw[jj];
    }
    __syncthreads();
  }
  #pragma unroll
  for (int i = 0; i < 8; i++) {
    int gm = m0 + ty * 8 + i;
    int b = gm / 600, t = gm % 600;
    #pragma unroll
    for (int jj = 0; jj < 8; jj++) {
      int n = n0 + tx * 8 + jj;
      float bia = (n < 512) ? P.bk[n] : P.bv[n - 512];
      float v = tanhf(acc[i][jj] + bia);
      if (n < 512) P.key_bt[(size_t)b * 307200 + (size_t)t * 512 + n] = v;
      else         P.val   [(size_t)b * 614400 + (size_t)t * 1024 + (n - 512)] = v;
    }
  }
}

// ---------------- persistent decoder: 4 groups x 64 blocks x 512 thr (8 b per group) ----------------
struct DecP {
  const float* Wq; const float* bq;
  const float* Wih_d; const float* Whh_d; const float* b_d;
  const float* Wc; const float* bc; const float* E;
  const int* flen;
  const float* key_bt; const float* val;
  float* h_d; float* c_d; float* last; float* q; float* ctx;
  float* scores;
  float* ctx_ch; float* Mch; float* Sch;
  float* out;
  u32* bar;
};

__global__ __launch_bounds__(512) void k_decoder(DecP P) {
  __shared__ float sm[16384];
  const int tid = threadIdx.x, bid = blockIdx.x;
  const int g = bid >> 6;            // batch group: b in [g*8, g*8+8)
  const int jb = bid & 63;
  u32 epoch = 0;
  u32* arrive = P.bar + g * 64;
  u32* flag   = P.bar + 272 + g;

  auto gsync = [&]() {
    VM_FENCE();
    __syncthreads();
    epoch++;
    const u32 target = 1000u + epoch;
    if (tid == 0)
      __hip_atomic_store(&arrive[jb], target, __ATOMIC_RELAXED, __HIP_MEMORY_SCOPE_AGENT);
    if (jb == (int)(epoch & 63u)) {
      if (tid < 16) {
        const int base = tid * 4;
        for (;;) {
          u32 a0 = __hip_atomic_load(&arrive[base + 0], __ATOMIC_RELAXED, __HIP_MEMORY_SCOPE_AGENT);
          u32 a1 = __hip_atomic_load(&arrive[base + 1], __ATOMIC_RELAXED, __HIP_MEMORY_SCOPE_AGENT);
          u32 a2 = __hip_atomic_load(&arrive[base + 2], __ATOMIC_RELAXED, __HIP_MEMORY_SCOPE_AGENT);
          u32 a3 = __hip_atomic_load(&arrive[base + 3], __ATOMIC_RELAXED, __HIP_MEMORY_SCOPE_AGENT);
          if (__all(umin4(a0, a1, a2, a3) >= target)) break;
          __builtin_amdgcn_s_sleep(1);
        }
        if (tid == 0)
          __hip_atomic_store(flag, target, __ATOMIC_RELAXED, __HIP_MEMORY_SCOPE_AGENT);
      }
    }
    if (tid == 0) {
      while (__hip_atomic_load(flag, __ATOMIC_RELAXED, __HIP_MEMORY_SCOPE_AGENT) < target)
        __builtin_amdgcn_s_sleep(2);
    }
    C_FENCE();
    __syncthreads();
  };

  // P1: gates + cell update. 8 b x 2048 gates over 64 blocks.
  auto phase_gates = [&](int i) {
    const int p = i & 1;
    const int b_lo = tid & 7;
    const int chunk = (tid >> 3) & 7;
    const int j_lo = tid >> 6;
    const int bG = g * 8 + b_lo;
    const int j = jb * 8 + j_lo;
    const float* hsrc = P.h_d + p * 16384;
    #pragma unroll
    for (int rr = 0; rr < 4; rr++) {
      float v[8];
      #pragma unroll
      for (int u = 0; u < 8; u++) {
        int idx = tid + (rr * 8 + u) * 512;
        int bb = idx >> 11, c = idx & 2047;
        int gb = g * 8 + bb;
        v[u] = (c < 512) ? ld_sys(&P.last[gb * 512 + c])
             : (c < 1536) ? ld_sys(&P.ctx[gb * 1024 + (c - 512)])
                          : ld_sys(&hsrc[gb * 512 + (c - 1536)]);
      }
      #pragma unroll
      for (int u = 0; u < 8; u++) {
        int idx = tid + (rr * 8 + u) * 512;
        int bb = idx >> 11, c = idx & 2047;
        sm[bb * 2048 + (c ^ (bb << 2))] = v[u];
      }
    }
    __syncthreads();
    const float* wbp; int rs, ko, k0;
    if (chunk < 6) { wbp = P.Wih_d; rs = 1536; ko = chunk * 256; k0 = chunk * 256; }
    else           { wbp = P.Whh_d; rs = 512;  ko = (chunk - 6) * 256; k0 = 1536 + (chunk - 6) * 256; }
    const float* r0 = wbp + (size_t)(j       ) * rs + ko;
    const float* r1 = wbp + (size_t)(512  + j) * rs + ko;
    const float* r2 = wbp + (size_t)(1024 + j) * rs + ko;
    const float* r3 = wbp + (size_t)(1536 + j) * rs + ko;
    const float* xb = sm + b_lo * 2048 + k0;
    const int xo = b_lo << 2;
    float a0 = 0.f, a1 = 0.f, a2 = 0.f, a3 = 0.f;
    #pragma unroll 4
    for (int k = 0; k < 256; k += 4) {
      float4 w0 = *(const float4*)(r0 + k);
      float4 w1 = *(const float4*)(r1 + k);
      float4 w2 = *(const float4*)(r2 + k);
      float4 w3 = *(const float4*)(r3 + k);
      float4 x  = *(const float4*)(xb + (k ^ xo));
      a0 += w0.x * x.x + w0.y * x.y + w0.z * x.z + w0.w * x.w;
      a1 += w1.x * x.x + w1.y * x.y + w1.z * x.z + w1.w * x.w;
      a2 += w2.x * x.x + w2.y * x.y + w2.z * x.z + w2.w * x.w;
      a3 += w3.x * x.x + w3.y * x.y + w3.z * x.z + w3.w * x.w;
    }
    a0 += __shfl_xor(a0, 8); a0 += __shfl_xor(a0, 16); a0 += __shfl_xor(a0, 32);
    a1 += __shfl_xor(a1, 8); a1 += __shfl_xor(a1, 16); a1 += __shfl_xor(a1, 32);
    a2 += __shfl_xor(a2, 8); a2 += __shfl_xor(a2, 16); a2 += __shfl_xor(a2, 32);
    a3 += __shfl_xor(a3, 8); a3 += __shfl_xor(a3, 16); a3 += __shfl_xor(a3, 32);
    if (chunk == 0) {
      float gi = a0 + P.b_d[j];
      float gf = a1 + P.b_d[512 + j];
      float gg = a2 + P.b_d[1024 + j];
      float go = a3 + P.b_d[1536 + j];
      int ci = bG * 512 + j;
      float co = P.c_d[ci];
      float cn = sigf(gf) * co + sigf(gi) * tanhf(gg);
      float hn = sigf(go) * tanhf(cn);
      P.c_d[ci] = cn;
      st_sys(&P.h_d[(p ^ 1) * 16384 + ci], hn);
    }
  };

  // P2: logits_i (1/thread over 8 b x 4096 v) + q_{i+1} (every 8th thread)
  auto phase_logits_q = [&](int i) {
    const int pn = (i & 1) ^ 1;
    const float* hsrc = P.h_d + pn * 16384;
    {
      float v[8];
      #pragma unroll
      for (int u = 0; u < 8; u++) {
        int idx = tid + u * 512;
        int bb = idx >> 9, k = idx & 511;
        v[u] = ld_sys(&hsrc[(g * 8 + bb) * 512 + k]);
      }
      #pragma unroll
      for (int u = 0; u < 8; u++) {
        int idx = tid + u * 512;
        int bb = idx >> 9, k = idx & 511;
        sm[bb * 512 + (k ^ (bb << 2))] = v[u];
      }
    }
    __syncthreads();
    if (i >= 0) {
      int pidx = jb * 512 + tid;         // 0..32767 = 8 b x 4096 v
      int bb = pidx & 7;
      int v = pidx >> 3;
      const float* w0 = P.Wc + (size_t)v * 512;
      const float* hbp = sm + bb * 512;
      const int xo = bb << 2;
      float s0 = 0.f;
      #pragma unroll 4
      for (int k = 0; k < 512; k += 4) {
        float4 A0 = *(const float4*)(w0 + k);
        int kx = k ^ xo;
        s0 += A0.x * hbp[kx] + A0.y * hbp[kx + 1] + A0.z * hbp[kx + 2] + A0.w * hbp[kx + 3];
      }
      st_sys(&P.out[(size_t)(g * 8 + bb) * 491520 + (size_t)i * 4096 + v], s0 + P.bc[v]);
    }
    if ((tid & 7) == 0) {
      int qp = jb * 64 + (tid >> 3);     // 0..4095 = 8 b x 512 d
      int bb = qp & 7;
      int d = qp >> 3;
      const float* w0 = P.Wq + (size_t)d * 512;
      const float* hbp = sm + bb * 512;
      const int xo = bb << 2;
      float s0 = 0.f;
      #pragma unroll 4
      for (int k = 0; k < 512; k += 4) {
        float4 A0 = *(const float4*)(w0 + k);
        int kx = k ^ xo;
        s0 += A0.x * hbp[kx] + A0.y * hbp[kx + 1] + A0.z * hbp[kx + 2] + A0.w * hbp[kx + 3];
      }
      st_sys(&P.q[(g * 8 + bb) * 512 + d], tanhf(s0 + P.bq[d]));
    }
  };

  // P3: scores + chunk-local softmax + val partial-dot. ALL 64 blocks: 8 b x 8 chunks x 75 t.
  auto phase_scores = [&]() {
    const int bloc = jb >> 3, ch = jb & 7;
    const int b = g * 8 + bloc;
    const int t0 = ch * 75;
    float* pl   = sm;           // [75] raw scores
    float* wmax = sm + 80;      // [8]
    float* pl2  = sm + 96;      // [75] exp weights
    float* wsum = sm + 176;     // [8]
    const int wv = tid >> 6, lane = tid & 63;
    const int kbase = lane * 8;
    const int len = P.flen[b];
    float qreg[8];
    {
      const float* qb = P.q + b * 512 + kbase;
      #pragma unroll
      for (int jj = 0; jj < 8; jj++) qreg[jj] = ld_sys(&qb[jj]);
    }
    const float* kb = P.key_bt + (size_t)b * 307200 + kbase;
    float mloc = -INFINITY;
    for (int t = t0 + wv; t < t0 + 75; t += 8) {
      const float4* kr = (const float4*)(kb + (size_t)t * 512);
      float4 u0 = kr[0];
      float4 u1 = kr[1];
      float s = qreg[0] * u0.x + qreg[1] * u0.y + qreg[2] * u0.z + qreg[3] * u0.w
              + qreg[4] * u1.x + qreg[5] * u1.y + qreg[6] * u1.z + qreg[7] * u1.w;
      s += __shfl_xor(s, 1);  s += __shfl_xor(s, 2);  s += __shfl_xor(s, 4);
      s += __shfl_xor(s, 8);  s += __shfl_xor(s, 16); s += __shfl_xor(s, 32);
      float sc = (t < len) ? 2.0f * s : -1e30f;
      if (lane == 0) { st_sys(&P.scores[b * 600 + t], sc); pl[t - t0] = sc; }
      mloc = fmaxf(mloc, sc);
    }
    if (lane == 0) wmax[wv] = mloc;
    __syncthreads();
    float M = fmaxf(fmaxf(fmaxf(wmax[0], wmax[1]), fmaxf(wmax[2], wmax[3])),
                    fmaxf(fmaxf(wmax[4], wmax[5]), fmaxf(wmax[6], wmax[7])));
    float pv = (tid < 75) ? expf(pl[tid] - M) : 0.f;
    if (tid < 75) pl2[tid] = pv;
    // per-wave sum of pv (S reduction off critical path)
    float ws = pv;
    ws += __shfl_xor(ws, 1);  ws += __shfl_xor(ws, 2);  ws += __shfl_xor(ws, 4);
    ws += __shfl_xor(ws, 8);  ws += __shfl_xor(ws, 16); ws += __shfl_xor(ws, 32);
    if (lane == 0) wsum[wv] = ws;
    __syncthreads();   // pl2 + wsum visible
    // val partial-dot: deep unroll, 16 outstanding loads per iteration
    const float* vb = P.val + (size_t)b * 614400 + (size_t)t0 * 1024 + tid;
    float acc0 = 0.f, acc1 = 0.f;
    int tt = 0;
    for (; tt + 8 <= 75; tt += 8) {
      float va[8], vc[8], pw[8];
      #pragma unroll
      for (int u = 0; u < 8; u++) {
        va[u] = vb[(size_t)(tt + u) * 1024];
        vc[u] = vb[(size_t)(tt + u) * 1024 + 512];
      }
      #pragma unroll
      for (int u = 0; u < 8; u++) pw[u] = pl2[tt + u];
      #pragma unroll
      for (int u = 0; u < 8; u++) { acc0 += pw[u] * va[u]; acc1 += pw[u] * vc[u]; }
    }
    for (; tt < 75; tt++) {
      float p0 = pl2[tt];
      acc0 += p0 * vb[(size_t)tt * 1024];
      acc1 += p0 * vb[(size_t)tt * 1024 + 512];
    }
    float* cc = P.ctx_ch + (size_t)(b * 8 + ch) * 1024;
    st_sys(&cc[tid], acc0);
    st_sys(&cc[tid + 512], acc1);
    if (tid == 0) {
      float S = wsum[0] + wsum[1] + wsum[2] + wsum[3]
              + wsum[4] + wsum[5] + wsum[6] + wsum[7];
      st_sys(&P.Mch[b * 8 + ch], M);
      st_sys(&P.Sch[b * 8 + ch], S);
    }
  };

  // P4: argmax_i (jb 0..7) || combine ctx + att_seq (jb 8..15)
  auto phase_post = [&](int i, int att_i) {
    if (jb < 8) {
      if (i < 0) return;
      const int b = g * 8 + jb;
      const int wv = tid >> 6, lane = tid & 63;
      const float* row = P.out + (size_t)b * 491520 + (size_t)i * 4096;
      float bv = -INFINITY; int bi = 0;
      for (int v = tid; v < 4096; v += 512) {
        float x = ld_sys(&row[v]);
        if (x > bv) { bv = x; bi = v; }    // ascending v per chain -> keeps first occurrence
      }
      // wave reduce (value, index) with first-occurrence tie rule
      #pragma unroll
      for (int m = 1; m < 64; m <<= 1) {
        float ov = __shfl_xor(bv, m);
        int oi = __shfl_xor(bi, m);
        if (ov > bv || (ov == bv && oi < bi)) { bv = ov; bi = oi; }
      }
      float* amax = sm;
      int* aidx = (int*)(sm + 8);
      int* resw = (int*)(sm + 16);
      if (lane == 0) { amax[wv] = bv; aidx[wv] = bi; }
      __syncthreads();
      if (tid == 0) {
        float best = amax[0]; int bidx = aidx[0];
        #pragma unroll
        for (int w2 = 1; w2 < 8; w2++) {
          float ov = amax[w2]; int oi = aidx[w2];
          if (ov > best || (ov == best && oi < bidx)) { best = ov; bidx = oi; }
        }
        resw[0] = bidx;
      }
      __syncthreads();
      int widx = resw[0];
      st_sys(&P.last[b * 512 + tid], P.E[(size_t)widx * 512 + tid]);
    } else if (jb < 16) {
      if (att_i < 0) return;
      const int b = g * 8 + (jb - 8);
      float Mc[8], Sc[8];
      #pragma unroll
      for (int c = 0; c < 8; c++) { Mc[c] = ld_sys(&P.Mch[b * 8 + c]); Sc[c] = ld_sys(&P.Sch[b * 8 + c]); }
      float M = Mc[0];
      #pragma unroll
      for (int c = 1; c < 8; c++) M = fmaxf(M, Mc[c]);
      float sca[8]; float L = 0.f;
      #pragma unroll
      for (int c = 0; c < 8; c++) { sca[c] = expf(Mc[c] - M); L += Sc[c] * sca[c]; }
      const float invL = 1.0f / L;
      for (int w = tid; w < 1024; w += 512) {
        float s = 0.f;
        #pragma unroll
        for (int c = 0; c < 8; c++)
          s += ld_sys(&P.ctx_ch[(size_t)(b * 8 + c) * 1024 + w]) * sca[c];
        st_sys(&P.ctx[b * 1024 + w], s * invL);
      }
      for (int t = tid; t < 600; t += 512) {
        float p = expf(ld_sys(&P.scores[b * 600 + t]) - M) * invL;
        P.out[15728640ull + (size_t)b * 72000 + (size_t)att_i * 600 + t] = p;
      }
    }
  };

  // ---- pipeline (per-group independent) ----
  phase_logits_q(-1);            // q_0
  gsync();
  phase_scores();                // scores_0 + chunk ctx
  gsync();
  phase_post(-1, 0);             // ctx_0, att_seq[:,0,:]
  gsync();
  for (int i = 0; i < 120; i++) {
    phase_gates(i);
    gsync();
    phase_logits_q(i);           // logits_i, q_{i+1}
    gsync();
    if (i < 119) {
      phase_scores();
      gsync();
      phase_post(i, i + 1);      // argmax_i || ctx_{i+1}, att_seq[:,i+1,:]
      gsync();
    } else {
      phase_post(119, -1);       // argmax_119 only
      gsync();
    }
  }
}

// ---------------- launch ----------------
extern "C" void kernel_launch(void* const* d_in, const int* in_sizes, int n_in,
                              void* d_out, int out_size, void* d_ws, size_t ws_size,
                              hipStream_t stream) {
  const float* audio = (const float*)d_in[0];
  const float* Wih_f = (const float*)d_in[1];
  const float* Whh_f = (const float*)d_in[2];
  const float* b_f   = (const float*)d_in[3];
  const float* Wih_b = (const float*)d_in[4];
  const float* Whh_b = (const float*)d_in[5];
  const float* b_b   = (const float*)d_in[6];
  const float* Wq    = (const float*)d_in[7];
  const float* bq    = (const float*)d_in[8];
  const float* Wk    = (const float*)d_in[9];
  const float* bk    = (const float*)d_in[10];
  const float* Wv    = (const float*)d_in[11];
  const float* bv    = (const float*)d_in[12];
  const float* Wih_d = (const float*)d_in[13];
  const float* Whh_d = (const float*)d_in[14];
  const float* b_d   = (const float*)d_in[15];
  const float* Wc    = (const float*)d_in[16];
  const float* bc    = (const float*)d_in[17];
  const float* E     = (const float*)d_in[18];
  const int*   flen  = (const int*)d_in[19];
  float* out = (float*)d_out;
  char* ws = (char*)d_ws;

  u32*   bar     = (u32*)  (ws + OFF_BAR);
  float* h_enc   = (float*)(ws + OFF_HENC);
  float* h_d     = (float*)(ws + OFF_HD);
  float* c_d     = (float*)(ws + OFF_CD);
  float* last    = (float*)(ws + OFF_LAST);
  float* qbuf    = (float*)(ws + OFF_Q);
  float* ctx     = (float*)(ws + OFF_CTX);
  float* scores  = (float*)(ws + OFF_SCORES);
  float* audio_T = (float*)(ws + OFF_AUDIOT);
  float* enc2    = (float*)(ws + OFF_ENC2);
  float* key_bt  = (float*)(ws + OFF_KEYT);
  float* val     = (float*)(ws + OFF_VAL);
  float* ctx_ch  = enc2;               // decoder reuses dead enc2 region
  float* Mch     = enc2 + 262144;      // 32*8*1024
  float* Sch     = Mch + 256;

  (void)hipMemsetAsync(ws, 0, STATE_BYTES, stream);
  k_init_last<<<64, 256, 0, stream>>>(E, last);
  k_prep_audio<<<(T_ * FIN_ * 32 + 255) / 256, 256, 0, stream>>>(audio, audio_T);

  EncP ep{audio_T, Wih_f, Whh_f, b_f, Wih_b, Whh_b, b_b, h_enc, enc2, bar};
  void* ea[] = { &ep };
  (void)hipLaunchCooperativeKernel((const void*)k_encoder, dim3(256), dim3(512), ea, 0, stream);

  KVP kp{enc2, Wk, bk, Wv, bv, key_bt, val};
  k_keyval<<<1800, 256, 0, stream>>>(kp);

  DecP dp{Wq, bq, Wih_d, Whh_d, b_d, Wc, bc, E, flen, key_bt, val,
          h_d, c_d, last, qbuf, ctx, scores, ctx_ch, Mch, Sch, out, bar};
  void* da[] = { &dp };
  (void)hipLaunchCooperativeKernel((const void*)k_decoder, dim3(256), dim3(512), da, 0, stream);
}

// Round 16
// 15557.275 us; speedup vs baseline: 1.9767x; 1.9767x over previous
//
#include <hip/hip_runtime.h>
#include <math.h>

typedef unsigned int u32;

#define T_    600
#define FIN_  120

// ---- ws byte offsets ----
#define OFF_BAR      0ull          // 2048 B: arrive[256]; enc flags 257..264; dec flags 272..275
#define OFF_HENC     2048ull       // [2 parity][2 dir][512][32]
#define OFF_CENC     264192ull     // (unused)
#define OFF_HD       395264ull     // [2 parity][32][512]
#define OFF_CD       526336ull     // [32][512]
#define STATE_BYTES  591872ull     // memset-0 region
#define OFF_LAST     591872ull     // [32][512]
#define OFF_Q        657408ull     // [32][512]
#define OFF_CTX      722944ull     // [32][1024]
#define OFF_SCORES   854016ull     // [32][600]
#define OFF_STATS    930816ull     // (legacy, unused)
#define OFF_AUDIOT   931840ull     // [600][120][32]
#define OFF_ENC2     10147840ull   // [32][1024][600]; decoder reuses: ctx_ch[32][8][1024], Mch, Sch
#define OFF_KEYT     88791040ull   // key_bt [32][600][512]
#define OFF_VAL      128112640ull  // val [32][600][1024]

__device__ __forceinline__ float sigf(float x) { return 1.0f / (1.0f + expf(-x)); }
__device__ __forceinline__ u32 umin4(u32 a, u32 b, u32 c, u32 d) {
  u32 x = a < b ? a : b; u32 y = c < d ? c : d; return x < y ? x : y;
}
// L3-coherent scalar access — bypasses non-coherent L2.
__device__ __forceinline__ void st_sys(float* p, float v) {
  __hip_atomic_store(p, v, __ATOMIC_RELAXED, __HIP_MEMORY_SCOPE_AGENT);
}
__device__ __forceinline__ float ld_sys(const float* p) {
  return __hip_atomic_load(p, __ATOMIC_RELAXED, __HIP_MEMORY_SCOPE_AGENT);
}
#define VM_FENCE() asm volatile("s_waitcnt vmcnt(0)" ::: "memory")
#define C_FENCE()  asm volatile("" ::: "memory")

// unified h+x LDS address: k in [0,632), b in [0,8). 2-float pad per 32-k chunk.
__device__ __forceinline__ int haddr(int k, int b) { return k * 8 + (k >> 5) * 2 + b; }

// ---------------- prep ----------------
__global__ __launch_bounds__(256) void k_prep_audio(const float* __restrict__ audio,
                                                    float* __restrict__ audio_T) {
  int idx = blockIdx.x * 256 + threadIdx.x;
  if (idx >= T_ * FIN_ * 32) return;
  int b = idx & 31;
  int r = idx >> 5;
  int f = r % FIN_;
  int t = r / FIN_;
  audio_T[idx] = audio[(size_t)b * (T_ * FIN_) + t * FIN_ + f];
}

__global__ __launch_bounds__(256) void k_init_last(const float* __restrict__ E,
                                                   float* __restrict__ last) {
  int idx = blockIdx.x * 256 + threadIdx.x;
  if (idx < 32 * 512) last[idx] = E[idx & 511];
}

// ---------------- persistent encoder: 8 groups (dir x bquad) x 32 blocks x 512 thr ----------------
// thread = (j_lo 16) x (kc 16) x (b_lo 2); 4 gates x 4 batches per thread; weight redundancy 2x.
struct EncP {
  const float* audio_T;
  const float* Wih_f; const float* Whh_f; const float* b_f;
  const float* Wih_b; const float* Whh_b; const float* b_b;
  float* h_enc; float* enc2;
  u32* bar;
};

__global__ __launch_bounds__(512) void k_encoder(EncP P) {
  __shared__ float hl[5096];          // unified h(512k)+x(120k) staged, k-major, chunk-padded
  __shared__ float hsave[4096];       // [128 r][32 slot] enc2 write-combine
  const int tid = threadIdx.x, bid = blockIdx.x;
  const int grp = bid >> 5;           // 0..7 = dir*4 + bquad
  const int dir = grp >> 2, bquad = grp & 3;
  const int jblk = bid & 31;
  const int j_lo = tid >> 5;          // 0..15
  const int kc   = (tid >> 1) & 15;   // 0..15
  const int b_lo = tid & 1;           // 0..1 -> batches b_lo*4 .. +4
  const int j = jblk * 16 + j_lo;
  const float* Wih  = dir ? P.Wih_b : P.Wih_f;
  const float* Whh  = dir ? P.Whh_b : P.Whh_f;
  const float* bias = dir ? P.b_b   : P.b_f;
  u32* arrive = P.bar + grp * 32;
  u32* flag   = P.bar + 257 + grp;

  const float* WA0 = Whh + (size_t)(j       ) * 512 + kc * 32;
  const float* WA1 = Whh + (size_t)(512  + j) * 512 + kc * 32;
  const float* WA2 = Whh + (size_t)(1024 + j) * 512 + kc * 32;
  const float* WA3 = Whh + (size_t)(1536 + j) * 512 + kc * 32;
  const float* IA0 = Wih + (size_t)(j       ) * 120 + kc * 8;
  const float* IA1 = Wih + (size_t)(512  + j) * 120 + kc * 8;
  const float* IA2 = Wih + (size_t)(1024 + j) * 120 + kc * 8;
  const float* IA3 = Wih + (size_t)(1536 + j) * 120 + kc * 8;
  const float bia0 = bias[j], bia1 = bias[512 + j], bia2 = bias[1024 + j], bia3 = bias[1536 + j];

  float c0 = 0.f, c1 = 0.f, c2 = 0.f, c3 = 0.f;   // cell states (kc==0 lanes)

  for (int s = 0; s < 600; s++) {
    const int t = dir ? (599 - s) : s;
    const int p = s & 1;
    // ---- stage h (k<512, ld_sys) + audio (k>=512, plain) : prefetch then write ----
    {
      const float* hsrc = P.h_enc + (size_t)(p * 2 + dir) * 16384 + bquad * 8;
      const float* xg = P.audio_T + (size_t)t * 3840 + bquad * 8;
      float v[10];
      #pragma unroll
      for (int u = 0; u < 10; u++) {
        int idx = u * 512 + tid;
        int k = idx >> 3, b = idx & 7;
        if (idx < 5056)
          v[u] = (k < 512) ? ld_sys(hsrc + k * 32 + b) : xg[(k - 512) * 32 + b];
      }
      #pragma unroll
      for (int u = 0; u < 10; u++) {
        int idx = u * 512 + tid;
        int k = idx >> 3, b = idx & 7;
        if (idx < 5056) hl[haddr(k, b)] = v[u];
      }
    }
    __syncthreads();

    // acc[gate][batch]
    float a00=0.f,a01=0.f,a02=0.f,a03=0.f;
    float a10=0.f,a11=0.f,a12=0.f,a13=0.f;
    float a20=0.f,a21=0.f,a22=0.f,a23=0.f;
    float a30=0.f,a31=0.f,a32=0.f,a33=0.f;
    const int boff = b_lo * 4;
    // Whh chunk: 32 k
    {
      const int k0 = kc * 32;
      #pragma unroll
      for (int m = 0; m < 32; m += 4) {
        float4 w0 = *(const float4*)(WA0 + m);
        float4 w1 = *(const float4*)(WA1 + m);
        float4 w2 = *(const float4*)(WA2 + m);
        float4 w3 = *(const float4*)(WA3 + m);
        const int base = (k0 + m) * 8 + kc * 2 + boff;
        #pragma unroll
        for (int d = 0; d < 4; d++) {
          float x0 = hl[base + d * 8 + 0];
          float x1 = hl[base + d * 8 + 1];
          float x2 = hl[base + d * 8 + 2];
          float x3 = hl[base + d * 8 + 3];
          float f0 = (d == 0) ? w0.x : (d == 1) ? w0.y : (d == 2) ? w0.z : w0.w;
          float f1 = (d == 0) ? w1.x : (d == 1) ? w1.y : (d == 2) ? w1.z : w1.w;
          float f2 = (d == 0) ? w2.x : (d == 1) ? w2.y : (d == 2) ? w2.z : w2.w;
          float f3 = (d == 0) ? w3.x : (d == 1) ? w3.y : (d == 2) ? w3.z : w3.w;
          a00 += f0 * x0; a01 += f0 * x1; a02 += f0 * x2; a03 += f0 * x3;
          a10 += f1 * x0; a11 += f1 * x1; a12 += f1 * x2; a13 += f1 * x3;
          a20 += f2 * x0; a21 += f2 * x1; a22 += f2 * x2; a23 += f2 * x3;
          a30 += f3 * x0; a31 += f3 * x1; a32 += f3 * x2; a33 += f3 * x3;
        }
      }
    }
    // Wih chunk: 8 k (kc < 15)
    if (kc < 15) {
      #pragma unroll
      for (int m = 0; m < 8; m += 4) {
        float4 w0 = *(const float4*)(IA0 + m);
        float4 w1 = *(const float4*)(IA1 + m);
        float4 w2 = *(const float4*)(IA2 + m);
        float4 w3 = *(const float4*)(IA3 + m);
        const int k = 512 + kc * 8 + m;
        const int base = k * 8 + (k >> 5) * 2 + boff;
        #pragma unroll
        for (int d = 0; d < 4; d++) {
          float x0 = hl[base + d * 8 + 0];
          float x1 = hl[base + d * 8 + 1];
          float x2 = hl[base + d * 8 + 2];
          float x3 = hl[base + d * 8 + 3];
          float f0 = (d == 0) ? w0.x : (d == 1) ? w0.y : (d == 2) ? w0.z : w0.w;
          float f1 = (d == 0) ? w1.x : (d == 1) ? w1.y : (d == 2) ? w1.z : w1.w;
          float f2 = (d == 0) ? w2.x : (d == 1) ? w2.y : (d == 2) ? w2.z : w2.w;
          float f3 = (d == 0) ? w3.x : (d == 1) ? w3.y : (d == 2) ? w3.z : w3.w;
          a00 += f0 * x0; a01 += f0 * x1; a02 += f0 * x2; a03 += f0 * x3;
          a10 += f1 * x0; a11 += f1 * x1; a12 += f1 * x2; a13 += f1 * x3;
          a20 += f2 * x0; a21 += f2 * x1; a22 += f2 * x2; a23 += f2 * x3;
          a30 += f3 * x0; a31 += f3 * x1; a32 += f3 * x2; a33 += f3 * x3;
        }
      }
    }
    // reduce across kc (lane bits 1..4)
    #pragma unroll
    for (int msk = 2; msk <= 16; msk <<= 1) {
      a00 += __shfl_xor(a00, msk); a01 += __shfl_xor(a01, msk);
      a02 += __shfl_xor(a02, msk); a03 += __shfl_xor(a03, msk);
      a10 += __shfl_xor(a10, msk); a11 += __shfl_xor(a11, msk);
      a12 += __shfl_xor(a12, msk); a13 += __shfl_xor(a13, msk);
      a20 += __shfl_xor(a20, msk); a21 += __shfl_xor(a21, msk);
      a22 += __shfl_xor(a22, msk); a23 += __shfl_xor(a23, msk);
      a30 += __shfl_xor(a30, msk); a31 += __shfl_xor(a31, msk);
      a32 += __shfl_xor(a32, msk); a33 += __shfl_xor(a33, msk);
    }
    if (kc == 0) {
      float* hdst = P.h_enc + (size_t)((p ^ 1) * 2 + dir) * 16384 + j * 32 + bquad * 8 + boff;
      {
        float cn = sigf(a10 + bia1) * c0 + sigf(a00 + bia0) * tanhf(a20 + bia2);
        c0 = cn;
        float hn = sigf(a30 + bia3) * tanhf(cn);
        st_sys(hdst + 0, hn);
        int r = j_lo * 8 + boff + 0; hsave[r * 32 + ((t + r) & 31)] = hn;
      }
      {
        float cn = sigf(a11 + bia1) * c1 + sigf(a01 + bia0) * tanhf(a21 + bia2);
        c1 = cn;
        float hn = sigf(a31 + bia3) * tanhf(cn);
        st_sys(hdst + 1, hn);
        int r = j_lo * 8 + boff + 1; hsave[r * 32 + ((t + r) & 31)] = hn;
      }
      {
        float cn = sigf(a12 + bia1) * c2 + sigf(a02 + bia0) * tanhf(a22 + bia2);
        c2 = cn;
        float hn = sigf(a32 + bia3) * tanhf(cn);
        st_sys(hdst + 2, hn);
        int r = j_lo * 8 + boff + 2; hsave[r * 32 + ((t + r) & 31)] = hn;
      }
      {
        float cn = sigf(a13 + bia1) * c3 + sigf(a03 + bia0) * tanhf(a23 + bia2);
        c3 = cn;
        float hn = sigf(a33 + bia3) * tanhf(cn);
        st_sys(hdst + 3, hn);
        int r = j_lo * 8 + boff + 3; hsave[r * 32 + ((t + r) & 31)] = hn;
      }
    }
    // ---- barrier + deferred enc2 flush ----
    VM_FENCE();
    __syncthreads();
    const u32 target = (u32)(s + 1);
    if (tid == 0)
      __hip_atomic_store(&arrive[jblk], target, __ATOMIC_RELAXED, __HIP_MEMORY_SCOPE_AGENT);
    {
      bool doflush = dir ? ((t & 31) == 0) : (((t & 31) == 31) || (t == 599));
      int tbase = dir ? t : ((t == 599) ? 576 : (t - 31));
      if (doflush) {
        const int fmaxv = 599 - tbase;
        for (int idx = tid; idx < 4096; idx += 512) {
          int r = idx >> 5, f = idx & 31;
          if (f <= fmaxv) {
            float v = hsave[r * 32 + ((tbase + f + r) & 31)];
            int jl = r >> 3, bl = r & 7;
            P.enc2[(size_t)(bquad * 8 + bl) * 614400 +
                   (size_t)(dir * 512 + jblk * 16 + jl) * 600 + tbase + f] = v;
          }
        }
      }
    }
    if (jblk == (s & 31)) {
      if (tid < 8) {
        const int base = tid * 4;
        for (;;) {
          u32 a0_ = __hip_atomic_load(&arrive[base + 0], __ATOMIC_RELAXED, __HIP_MEMORY_SCOPE_AGENT);
          u32 a1_ = __hip_atomic_load(&arrive[base + 1], __ATOMIC_RELAXED, __HIP_MEMORY_SCOPE_AGENT);
          u32 a2_ = __hip_atomic_load(&arrive[base + 2], __ATOMIC_RELAXED, __HIP_MEMORY_SCOPE_AGENT);
          u32 a3_ = __hip_atomic_load(&arrive[base + 3], __ATOMIC_RELAXED, __HIP_MEMORY_SCOPE_AGENT);
          if (__all(umin4(a0_, a1_, a2_, a3_) >= target)) break;
          __builtin_amdgcn_s_sleep(1);
        }
        if (tid == 0)
          __hip_atomic_store(flag, target, __ATOMIC_RELAXED, __HIP_MEMORY_SCOPE_AGENT);
      }
    }
    if (tid == 0) {
      while (__hip_atomic_load(flag, __ATOMIC_RELAXED, __HIP_MEMORY_SCOPE_AGENT) < target)
        __builtin_amdgcn_s_sleep(2);
    }
    C_FENCE();
    __syncthreads();
  }
}

// ---------------- key/val GEMM: key -> [b][t][k], val -> [b][t][w] ----------------
struct KVP {
  const float* enc2; const float* Wk; const float* bk; const float* Wv; const float* bv;
  float* key_bt; float* val;
};

__global__ __launch_bounds__(256) void k_keyval(KVP P) {
  __shared__ float As[16 * 132];
  __shared__ float Bs[16 * 132];
  const int tid = threadIdx.x, bid = blockIdx.x;
  const int mt = bid % 150, nt = bid / 150;
  const int m0 = mt * 128, n0 = nt * 128;
  const int tx = tid & 15, ty = tid >> 4;
  const int mmS = tid & 127;
  const int gmS = m0 + mmS;
  const int bS = gmS / 600, tS = gmS % 600;
  const int kkS0 = tid >> 7;
  const int nnS0 = tid >> 4;
  const int kkSB = tid & 15;
  float acc[8][8];
  #pragma unroll
  for (int i = 0; i < 8; i++)
    #pragma unroll
    for (int jj = 0; jj < 8; jj++) acc[i][jj] = 0.f;
  for (int k0 = 0; k0 < 1024; k0 += 16) {
    #pragma unroll
    for (int r = 0; r < 8; r++) {
      int kk = kkS0 + 2 * r;
      As[kk * 132 + mmS] = P.enc2[(size_t)bS * 614400 + (size_t)(k0 + kk) * 600 + tS];
    }
    #pragma unroll
    for (int r = 0; r < 8; r++) {
      int nn = nnS0 + 16 * r;
      int n = n0 + nn;
      const float* src = (n < 512) ? (P.Wk + (size_t)n * 1024) : (P.Wv + (size_t)(n - 512) * 1024);
      Bs[kkSB * 132 + nn] = src[k0 + kkSB];
    }
    __syncthreads();
    #pragma unroll
    for (int kk = 0; kk < 16; kk++) {
      float4 A0 = *(const float4*)&As[kk * 132 + ty * 8];
      float4 A1 = *(const float4*)&As[kk * 132 + ty * 8 + 4];
      float4 B0 = *(const float4*)&Bs[kk * 132 + tx * 8];
      float4 B1 = *(const float4*)&Bs[kk * 132 + tx * 8 + 4];
      float av[8] = {A0.x, A0.y, A0.z, A0.w, A1.x, A1.y, A1.z, A1.w};
      float bw[8] = {B0.x, B0.y, B0.z, B0.w, B1.x, B1.y, B1.z, B1.w};
      #pragma unroll
      for (int i = 0; i < 8; i++)
        #pragma unroll
        for (int jj = 0; jj < 8; jj++) acc[i][jj] += av[i] * bw[jj];
    }
    __syncthreads();
  }
  #pragma unroll
  for (int i = 0; i < 8; i++) {
    int gm = m0 + ty * 8 + i;
    int b = gm / 600, t = gm % 600;
    #pragma unroll
    for (int jj = 0; jj < 8; jj++) {
      int n = n0 + tx * 8 + jj;
      float bia = (n < 512) ? P.bk[n] : P.bv[n - 512];
      float v = tanhf(acc[i][jj] + bia);
      if (n < 512) P.key_bt[(size_t)b * 307200 + (size_t)t * 512 + n] = v;
      else         P.val   [(size_t)b * 614400 + (size_t)t * 1024 + (n - 512)] = v;
    }
  }
}

// ---------------- persistent decoder: 4 groups x 64 blocks x 512 thr (8 b per group) ----------------
struct DecP {
  const float* Wq; const float* bq;
  const float* Wih_d; const float* Whh_d; const float* b_d;
  const float* Wc; const float* bc; const float* E;
  const int* flen;
  const float* key_bt; const float* val;
  float* h_d; float* c_d; float* last; float* q; float* ctx;
  float* scores;
  float* ctx_ch; float* Mch; float* Sch;
  float* out;
  u32* bar;
};

__global__ __launch_bounds__(512) void k_decoder(DecP P) {
  __shared__ float sm[16384];
  const int tid = threadIdx.x, bid = blockIdx.x;
  const int g = bid >> 6;            // batch group: b in [g*8, g*8+8)
  const int jb = bid & 63;
  u32 epoch = 0;
  u32* arrive = P.bar + g * 64;
  u32* flag   = P.bar + 272 + g;

  auto gsync = [&]() {
    VM_FENCE();
    __syncthreads();
    epoch++;
    const u32 target = 1000u + epoch;
    if (tid == 0)
      __hip_atomic_store(&arrive[jb], target, __ATOMIC_RELAXED, __HIP_MEMORY_SCOPE_AGENT);
    if (jb == (int)(epoch & 63u)) {
      if (tid < 16) {
        const int base = tid * 4;
        for (;;) {
          u32 a0 = __hip_atomic_load(&arrive[base + 0], __ATOMIC_RELAXED, __HIP_MEMORY_SCOPE_AGENT);
          u32 a1 = __hip_atomic_load(&arrive[base + 1], __ATOMIC_RELAXED, __HIP_MEMORY_SCOPE_AGENT);
          u32 a2 = __hip_atomic_load(&arrive[base + 2], __ATOMIC_RELAXED, __HIP_MEMORY_SCOPE_AGENT);
          u32 a3 = __hip_atomic_load(&arrive[base + 3], __ATOMIC_RELAXED, __HIP_MEMORY_SCOPE_AGENT);
          if (__all(umin4(a0, a1, a2, a3) >= target)) break;
          __builtin_amdgcn_s_sleep(1);
        }
        if (tid == 0)
          __hip_atomic_store(flag, target, __ATOMIC_RELAXED, __HIP_MEMORY_SCOPE_AGENT);
      }
    }
    if (tid == 0) {
      while (__hip_atomic_load(flag, __ATOMIC_RELAXED, __HIP_MEMORY_SCOPE_AGENT) < target)
        __builtin_amdgcn_s_sleep(2);
    }
    C_FENCE();
    __syncthreads();
  };

  // P1: gates + cell update. 8 b x 2048 gates over 64 blocks.
  auto phase_gates = [&](int i) {
    const int p = i & 1;
    const int b_lo = tid & 7;
    const int chunk = (tid >> 3) & 7;
    const int j_lo = tid >> 6;
    const int bG = g * 8 + b_lo;
    const int j = jb * 8 + j_lo;
    const float* hsrc = P.h_d + p * 16384;
    #pragma unroll
    for (int rr = 0; rr < 4; rr++) {
      float v[8];
      #pragma unroll
      for (int u = 0; u < 8; u++) {
        int idx = tid + (rr * 8 + u) * 512;
        int bb = idx >> 11, c = idx & 2047;
        int gb = g * 8 + bb;
        v[u] = (c < 512) ? ld_sys(&P.last[gb * 512 + c])
             : (c < 1536) ? ld_sys(&P.ctx[gb * 1024 + (c - 512)])
                          : ld_sys(&hsrc[gb * 512 + (c - 1536)]);
      }
      #pragma unroll
      for (int u = 0; u < 8; u++) {
        int idx = tid + (rr * 8 + u) * 512;
        int bb = idx >> 11, c = idx & 2047;
        sm[bb * 2048 + (c ^ (bb << 2))] = v[u];
      }
    }
    __syncthreads();
    const float* wbp; int rs, ko, k0;
    if (chunk < 6) { wbp = P.Wih_d; rs = 1536; ko = chunk * 256; k0 = chunk * 256; }
    else           { wbp = P.Whh_d; rs = 512;  ko = (chunk - 6) * 256; k0 = 1536 + (chunk - 6) * 256; }
    const float* r0 = wbp + (size_t)(j       ) * rs + ko;
    const float* r1 = wbp + (size_t)(512  + j) * rs + ko;
    const float* r2 = wbp + (size_t)(1024 + j) * rs + ko;
    const float* r3 = wbp + (size_t)(1536 + j) * rs + ko;
    const float* xb = sm + b_lo * 2048 + k0;
    const int xo = b_lo << 2;
    float a0 = 0.f, a1 = 0.f, a2 = 0.f, a3 = 0.f;
    #pragma unroll 4
    for (int k = 0; k < 256; k += 4) {
      float4 w0 = *(const float4*)(r0 + k);
      float4 w1 = *(const float4*)(r1 + k);
      float4 w2 = *(const float4*)(r2 + k);
      float4 w3 = *(const float4*)(r3 + k);
      float4 x  = *(const float4*)(xb + (k ^ xo));
      a0 += w0.x * x.x + w0.y * x.y + w0.z * x.z + w0.w * x.w;
      a1 += w1.x * x.x + w1.y * x.y + w1.z * x.z + w1.w * x.w;
      a2 += w2.x * x.x + w2.y * x.y + w2.z * x.z + w2.w * x.w;
      a3 += w3.x * x.x + w3.y * x.y + w3.z * x.z + w3.w * x.w;
    }
    a0 += __shfl_xor(a0, 8); a0 += __shfl_xor(a0, 16); a0 += __shfl_xor(a0, 32);
    a1 += __shfl_xor(a1, 8); a1 += __shfl_xor(a1, 16); a1 += __shfl_xor(a1, 32);
    a2 += __shfl_xor(a2, 8); a2 += __shfl_xor(a2, 16); a2 += __shfl_xor(a2, 32);
    a3 += __shfl_xor(a3, 8); a3 += __shfl_xor(a3, 16); a3 += __shfl_xor(a3, 32);
    if (chunk == 0) {
      float gi = a0 + P.b_d[j];
      float gf = a1 + P.b_d[512 + j];
      float gg = a2 + P.b_d[1024 + j];
      float go = a3 + P.b_d[1536 + j];
      int ci = bG * 512 + j;
      float co = P.c_d[ci];
      float cn = sigf(gf) * co + sigf(gi) * tanhf(gg);
      float hn = sigf(go) * tanhf(cn);
      P.c_d[ci] = cn;
      st_sys(&P.h_d[(p ^ 1) * 16384 + ci], hn);
    }
  };

  // P2: logits_i (1/thread over 8 b x 4096 v) + q_{i+1} (every 8th thread)
  auto phase_logits_q = [&](int i) {
    const int pn = (i & 1) ^ 1;
    const float* hsrc = P.h_d + pn * 16384;
    {
      float v[8];
      #pragma unroll
      for (int u = 0; u < 8; u++) {
        int idx = tid + u * 512;
        int bb = idx >> 9, k = idx & 511;
        v[u] = ld_sys(&hsrc[(g * 8 + bb) * 512 + k]);
      }
      #pragma unroll
      for (int u = 0; u < 8; u++) {
        int idx = tid + u * 512;
        int bb = idx >> 9, k = idx & 511;
        sm[bb * 512 + (k ^ (bb << 2))] = v[u];
      }
    }
    __syncthreads();
    if (i >= 0) {
      int pidx = jb * 512 + tid;         // 0..32767 = 8 b x 4096 v
      int bb = pidx & 7;
      int v = pidx >> 3;
      const float* w0 = P.Wc + (size_t)v * 512;
      const float* hbp = sm + bb * 512;
      const int xo = bb << 2;
      float s0 = 0.f;
      #pragma unroll 4
      for (int k = 0; k < 512; k += 4) {
        float4 A0 = *(const float4*)(w0 + k);
        int kx = k ^ xo;
        s0 += A0.x * hbp[kx] + A0.y * hbp[kx + 1] + A0.z * hbp[kx + 2] + A0.w * hbp[kx + 3];
      }
      st_sys(&P.out[(size_t)(g * 8 + bb) * 491520 + (size_t)i * 4096 + v], s0 + P.bc[v]);
    }
    if ((tid & 7) == 0) {
      int qp = jb * 64 + (tid >> 3);     // 0..4095 = 8 b x 512 d
      int bb = qp & 7;
      int d = qp >> 3;
      const float* w0 = P.Wq + (size_t)d * 512;
      const float* hbp = sm + bb * 512;
      const int xo = bb << 2;
      float s0 = 0.f;
      #pragma unroll 4
      for (int k = 0; k < 512; k += 4) {
        float4 A0 = *(const float4*)(w0 + k);
        int kx = k ^ xo;
        s0 += A0.x * hbp[kx] + A0.y * hbp[kx + 1] + A0.z * hbp[kx + 2] + A0.w * hbp[kx + 3];
      }
      st_sys(&P.q[(g * 8 + bb) * 512 + d], tanhf(s0 + P.bq[d]));
    }
  };

  // P3: scores + chunk-local softmax + val partial-dot. ALL 64 blocks: 8 b x 8 chunks x 75 t.
  auto phase_scores = [&]() {
    const int bloc = jb >> 3, ch = jb & 7;
    const int b = g * 8 + bloc;
    const int t0 = ch * 75;
    float* pl   = sm;           // [75] raw scores
    float* wmax = sm + 80;      // [8]
    float* pl2  = sm + 96;      // [75] exp weights
    float* red  = sm + 256;     // [512]
    const int wv = tid >> 6, lane = tid & 63;
    const int kbase = lane * 8;
    const int len = P.flen[b];
    float qreg[8];
    {
      const float* qb = P.q + b * 512 + kbase;
      #pragma unroll
      for (int jj = 0; jj < 8; jj++) qreg[jj] = ld_sys(&qb[jj]);
    }
    const float* kb = P.key_bt + (size_t)b * 307200 + kbase;
    float mloc = -INFINITY;
    for (int t = t0 + wv; t < t0 + 75; t += 8) {
      const float4* kr = (const float4*)(kb + (size_t)t * 512);
      float4 u0 = kr[0];
      float4 u1 = kr[1];
      float s = qreg[0] * u0.x + qreg[1] * u0.y + qreg[2] * u0.z + qreg[3] * u0.w
              + qreg[4] * u1.x + qreg[5] * u1.y + qreg[6] * u1.z + qreg[7] * u1.w;
      s += __shfl_xor(s, 1);  s += __shfl_xor(s, 2);  s += __shfl_xor(s, 4);
      s += __shfl_xor(s, 8);  s += __shfl_xor(s, 16); s += __shfl_xor(s, 32);
      float sc = (t < len) ? 2.0f * s : -1e30f;
      if (lane == 0) { st_sys(&P.scores[b * 600 + t], sc); pl[t - t0] = sc; }
      mloc = fmaxf(mloc, sc);
    }
    if (lane == 0) wmax[wv] = mloc;
    __syncthreads();
    float M = fmaxf(fmaxf(fmaxf(wmax[0], wmax[1]), fmaxf(wmax[2], wmax[3])),
                    fmaxf(fmaxf(wmax[4], wmax[5]), fmaxf(wmax[6], wmax[7])));
    float pv = (tid < 75) ? expf(pl[tid] - M) : 0.f;
    if (tid < 75) pl2[tid] = pv;
    red[tid] = pv;
    __syncthreads();
    for (int off = 256; off > 0; off >>= 1) {
      if (tid < off) red[tid] += red[tid + off];
      __syncthreads();
    }
    const float S = red[0];
    // val partial-dot: w = tid and tid+512 over 75 t, 4 independent chains
    const float* vb = P.val + (size_t)b * 614400 + (size_t)t0 * 1024 + tid;
    float a00 = 0.f, a01 = 0.f, a10 = 0.f, a11 = 0.f;
    #pragma unroll 4
    for (int tt = 0; tt < 74; tt += 2) {
      float p0 = pl2[tt], p1 = pl2[tt + 1];
      a00 += p0 * vb[(size_t)tt * 1024];
      a01 += p0 * vb[(size_t)tt * 1024 + 512];
      a10 += p1 * vb[(size_t)(tt + 1) * 1024];
      a11 += p1 * vb[(size_t)(tt + 1) * 1024 + 512];
    }
    {
      float p0 = pl2[74];
      a00 += p0 * vb[(size_t)74 * 1024];
      a01 += p0 * vb[(size_t)74 * 1024 + 512];
    }
    float* cc = P.ctx_ch + (size_t)(b * 8 + ch) * 1024;
    st_sys(&cc[tid], a00 + a10);
    st_sys(&cc[tid + 512], a01 + a11);
    if (tid == 0) { st_sys(&P.Mch[b * 8 + ch], M); st_sys(&P.Sch[b * 8 + ch], S); }
  };

  // P4: argmax_i (jb 0..7) || combine ctx + att_seq (jb 8..15)
  auto phase_post = [&](int i, int att_i) {
    if (jb < 8) {
      if (i < 0) return;
      const int b = g * 8 + jb;
      const float* row = P.out + (size_t)b * 491520 + (size_t)i * 4096;
      float bv = -INFINITY; int bi = 0;
      for (int v = tid; v < 4096; v += 512) {
        float x = ld_sys(&row[v]);
        if (x > bv) { bv = x; bi = v; }
      }
      float* smax = sm;
      int* sidx = (int*)(sm + 512);
      smax[tid] = bv; sidx[tid] = bi;
      __syncthreads();
      for (int off = 256; off > 0; off >>= 1) {
        if (tid < off) {
          float ov = smax[tid + off]; int oi = sidx[tid + off];
          if (ov > smax[tid] || (ov == smax[tid] && oi < sidx[tid])) { smax[tid] = ov; sidx[tid] = oi; }
        }
        __syncthreads();
      }
      int widx = sidx[0];
      st_sys(&P.last[b * 512 + tid], P.E[(size_t)widx * 512 + tid]);
    } else if (jb < 16) {
      if (att_i < 0) return;
      const int b = g * 8 + (jb - 8);
      float Mc[8], Sc[8];
      #pragma unroll
      for (int c = 0; c < 8; c++) { Mc[c] = ld_sys(&P.Mch[b * 8 + c]); Sc[c] = ld_sys(&P.Sch[b * 8 + c]); }
      float M = Mc[0];
      #pragma unroll
      for (int c = 1; c < 8; c++) M = fmaxf(M, Mc[c]);
      float sca[8]; float L = 0.f;
      #pragma unroll
      for (int c = 0; c < 8; c++) { sca[c] = expf(Mc[c] - M); L += Sc[c] * sca[c]; }
      const float invL = 1.0f / L;
      for (int w = tid; w < 1024; w += 512) {
        float s = 0.f;
        #pragma unroll
        for (int c = 0; c < 8; c++)
          s += ld_sys(&P.ctx_ch[(size_t)(b * 8 + c) * 1024 + w]) * sca[c];
        st_sys(&P.ctx[b * 1024 + w], s * invL);
      }
      for (int t = tid; t < 600; t += 512) {
        float p = expf(ld_sys(&P.scores[b * 600 + t]) - M) * invL;
        P.out[15728640ull + (size_t)b * 72000 + (size_t)att_i * 600 + t] = p;
      }
    }
  };

  // ---- pipeline (per-group independent) ----
  phase_logits_q(-1);            // q_0
  gsync();
  phase_scores();                // scores_0 + chunk ctx
  gsync();
  phase_post(-1, 0);             // ctx_0, att_seq[:,0,:]
  gsync();
  for (int i = 0; i < 120; i++) {
    phase_gates(i);
    gsync();
    phase_logits_q(i);           // logits_i, q_{i+1}
    gsync();
    if (i < 119) {
      phase_scores();
      gsync();
      phase_post(i, i + 1);      // argmax_i || ctx_{i+1}, att_seq[:,i+1,:]
      gsync();
    } else {
      phase_post(119, -1);       // argmax_119 only
      gsync();
    }
  }
}

// ---------------- launch ----------------
extern "C" void kernel_launch(void* const* d_in, const int* in_sizes, int n_in,
                              void* d_out, int out_size, void* d_ws, size_t ws_size,
                              hipStream_t stream) {
  const float* audio = (const float*)d_in[0];
  const float* Wih_f = (const float*)d_in[1];
  const float* Whh_f = (const float*)d_in[2];
  const float* b_f   = (const float*)d_in[3];
  const float* Wih_b = (const float*)d_in[4];
  const float* Whh_b = (const float*)d_in[5];
  const float* b_b   = (const float*)d_in[6];
  const float* Wq    = (const float*)d_in[7];
  const float* bq    = (const float*)d_in[8];
  const float* Wk    = (const float*)d_in[9];
  const float* bk    = (const float*)d_in[10];
  const float* Wv    = (const float*)d_in[11];
  const float* bv    = (const float*)d_in[12];
  const float* Wih_d = (const float*)d_in[13];
  const float* Whh_d = (const float*)d_in[14];
  const float* b_d   = (const float*)d_in[15];
  const float* Wc    = (const float*)d_in[16];
  const float* bc    = (const float*)d_in[17];
  const float* E     = (const float*)d_in[18];
  const int*   flen  = (const int*)d_in[19];
  float* out = (float*)d_out;
  char* ws = (char*)d_ws;

  u32*   bar     = (u32*)  (ws + OFF_BAR);
  float* h_enc   = (float*)(ws + OFF_HENC);
  float* h_d     = (float*)(ws + OFF_HD);
  float* c_d     = (float*)(ws + OFF_CD);
  float* last    = (float*)(ws + OFF_LAST);
  float* qbuf    = (float*)(ws + OFF_Q);
  float* ctx     = (float*)(ws + OFF_CTX);
  float* scores  = (float*)(ws + OFF_SCORES);
  float* audio_T = (float*)(ws + OFF_AUDIOT);
  float* enc2    = (float*)(ws + OFF_ENC2);
  float* key_bt  = (float*)(ws + OFF_KEYT);
  float* val     = (float*)(ws + OFF_VAL);
  float* ctx_ch  = enc2;               // decoder reuses dead enc2 region
  float* Mch     = enc2 + 262144;      // 32*8*1024
  float* Sch     = Mch + 256;

  (void)hipMemsetAsync(ws, 0, STATE_BYTES, stream);
  k_init_last<<<64, 256, 0, stream>>>(E, last);
  k_prep_audio<<<(T_ * FIN_ * 32 + 255) / 256, 256, 0, stream>>>(audio, audio_T);

  EncP ep{audio_T, Wih_f, Whh_f, b_f, Wih_b, Whh_b, b_b, h_enc, enc2, bar};
  void* ea[] = { &ep };
  (void)hipLaunchCooperativeKernel((const void*)k_encoder, dim3(256), dim3(512), ea, 0, stream);

  KVP kp{enc2, Wk, bk, Wv, bv, key_bt, val};
  k_keyval<<<1800, 256, 0, stream>>>(kp);

  DecP dp{Wq, bq, Wih_d, Whh_d, b_d, Wc, bc, E, flen, key_bt, val,
          h_d, c_d, last, qbuf, ctx, scores, ctx_ch, Mch, Sch, out, bar};
  void* da[] = { &dp };
  (void)hipLaunchCooperativeKernel((const void*)k_decoder, dim3(256), dim3(512), da, 0, stream);
}